// Round 1
// baseline (683.560 us; speedup 1.0000x reference)
//
#include <hip/hip_runtime.h>
#include <hip/hip_bf16.h>

// ProbAttention (Informer ProbSparse) on MI355X.
// Shapes: queries/keys/values (4, 4096, 8, 64) f32 in (b, l, h, d) layout.
// index_sample (4096, 45) int32. Output context (b, h, 4096, 64) f32.
//
// Pipeline (all fp32 — no fp32 MFMA on CDNA4; precision needed for top-k):
//   K1 compute_m : m[b,h,l] = max_s(q.k_samp) - sum_s(q.k_samp)/4096
//   K2 topk      : per (b,h) top-45 indices of m (tie: lowest index)
//   K3a meanv    : mean over l of v per (b,h,d)
//   K3b fill     : out[...] = meanv broadcast (32 MB write)
//   K4 scores    : split-K flash: per (b,h, key-chunk of 256): partial
//                  softmax(Qr K^T * 0.125) and partial P@V -> ws
//   K5 combine   : merge 16 chunk partials, scatter to out rows m_top[u]

#define NB 4
#define NH 8
#define NL 4096
#define ND 64
#define NS 45          // U = n_top = 45
#define SCALE 0.125f   // 1/sqrt(64)
#define NCHUNK 16
#define CHUNK 256

static __device__ __forceinline__ float neg_inf() { return -__builtin_inff(); }

// ---------------- K1: sampled-dot m ----------------
// One wave per (b,h,l). Lane s < 45 computes dot(q[l], k[idx[l,s]]) over 64.
__global__ __launch_bounds__(256) void k_compute_m(
    const float* __restrict__ q, const float* __restrict__ k,
    const int* __restrict__ idxs, float* __restrict__ m_out)
{
  int gb = blockIdx.x;
  int xcd = gb & 7, seq = gb >> 3;          // XCD-locality swizzle: 4 bh per XCD
  int bh = xcd * 4 + (seq >> 10);
  int lblk = seq & 1023;
  int wid = threadIdx.x >> 6;
  int lane = threadIdx.x & 63;
  int b = bh >> 3, h = bh & 7;
  int l = lblk * 4 + wid;
  int s = (lane < NS) ? lane : 0;
  int ki = idxs[l * NS + s];
  const float4* q4 = (const float4*)(q + ((size_t)(b * NL + l) * NH + h) * ND);
  const float4* k4 = (const float4*)(k + ((size_t)(b * NL + ki) * NH + h) * ND);
  float dot = 0.f;
#pragma unroll
  for (int j = 0; j < 16; j++) {
    float4 qq = q4[j];  // uniform across wave -> broadcast
    float4 kk = k4[j];
    dot += qq.x * kk.x + qq.y * kk.y + qq.z * kk.z + qq.w * kk.w;
  }
  float mx = (lane < NS) ? dot : neg_inf();
  float sm = (lane < NS) ? dot : 0.f;
#pragma unroll
  for (int off = 32; off; off >>= 1) {
    mx = fmaxf(mx, __shfl_xor(mx, off));
    sm += __shfl_xor(sm, off);
  }
  if (lane == 0) m_out[bh * NL + l] = mx - sm * (1.0f / 4096.0f);
}

// ---------------- K2: top-45 per (b,h) ----------------
// Iterative argmax, 45 rounds. Tie-break: lower index wins (matches lax.top_k).
__global__ __launch_bounds__(256) void k_topk(
    const float* __restrict__ m_in, int* __restrict__ mtop)
{
  __shared__ float vals[NL];
  __shared__ unsigned long long red[256];
  int bh = blockIdx.x;
  int t = threadIdx.x;
  for (int i = t; i < NL; i += 256) vals[i] = m_in[bh * NL + i];
  __syncthreads();
  for (int it = 0; it < NS; ++it) {
    unsigned long long best = 0ull;
    for (int i = t; i < NL; i += 256) {
      float v = vals[i];
      unsigned u = __float_as_uint(v);
      u ^= (u >> 31) ? 0xFFFFFFFFu : 0x80000000u;  // monotone mapping
      unsigned long long key =
          ((unsigned long long)u << 32) | (unsigned)(~(unsigned)i);
      if (key > best) best = key;
    }
    red[t] = best;
    __syncthreads();
    for (int off = 128; off; off >>= 1) {
      if (t < off) { if (red[t + off] > red[t]) red[t] = red[t + off]; }
      __syncthreads();
    }
    if (t == 0) {
      int idx = (int)(~(unsigned)(red[0] & 0xFFFFFFFFull));
      mtop[bh * NS + it] = idx;
      vals[idx] = neg_inf();
    }
    __syncthreads();
  }
}

// ---------------- K3a: mean of v over l ----------------
__global__ __launch_bounds__(256) void k_meanv(
    const float* __restrict__ v, float* __restrict__ meanv)
{
  __shared__ float part[4][ND];
  int bh = blockIdx.x;
  int b = bh >> 3, h = bh & 7;
  int t = threadIdx.x, d = t & 63, g = t >> 6;
  float acc = 0.f;
  for (int l = g; l < NL; l += 4)
    acc += v[((size_t)(b * NL + l) * NH + h) * ND + d];
  part[g][d] = acc;
  __syncthreads();
  if (g == 0) {
    float s = part[0][d] + part[1][d] + part[2][d] + part[3][d];
    meanv[bh * ND + d] = s * (1.0f / 4096.0f);
  }
}

// ---------------- K3b: fill output with meanv ----------------
__global__ __launch_bounds__(256) void k_fill(
    const float* __restrict__ meanv, float4* __restrict__ out4)
{
  const int total = NB * NH * NL * ND / 4;  // 2M float4
  const float4* mv4 = (const float4*)meanv;
  for (int i = blockIdx.x * 256 + threadIdx.x; i < total; i += gridDim.x * 256) {
    int bh = i >> 16;       // 65536 float4 per (b,h)
    int d4 = i & 15;
    out4[i] = mv4[bh * 16 + d4];
  }
}

// ---------------- K4: split-K scores+softmax+PV partials ----------------
// Block = (b,h, chunk of 256 keys), 256 threads (4 waves).
__global__ __launch_bounds__(256) void k_scores(
    const float* __restrict__ q, const float* __restrict__ k,
    const float* __restrict__ v, const int* __restrict__ mtop,
    float* __restrict__ mc_out, float* __restrict__ lc_out,
    float* __restrict__ op_out)
{
  __shared__ float QLDS[NS * ND];     // 45x64
  __shared__ float SLDS[NS * 260];    // 45 rows, 260-stride (pad), cols 0..255
  __shared__ int mt[NS];
  __shared__ float mcs[NS], lcs[NS];

  int gb = blockIdx.x;
  int xcd = gb & 7, seq = gb >> 3;    // 512 blocks: 4 bh per XCD
  int bh = xcd * 4 + (seq >> 4);
  int c = seq & 15;
  int b = bh >> 3, h = bh & 7;
  int t = threadIdx.x;
  int wid = t >> 6, lane = t & 63;

  if (t < NS) mt[t] = mtop[bh * NS + t];
  __syncthreads();

  // stage Qr (45 rows) into LDS
  const float4* q4 = (const float4*)q;
  float4* QL4 = (float4*)QLDS;
  for (int i = t; i < NS * 16; i += 256) {
    int u = i >> 4, j = i & 15;
    QL4[i] = q4[((size_t)(b * NL + mt[u]) * NH + h) * 16 + j];
  }
  __syncthreads();

  // Phase B: thread t owns key column kk=t; K row held in 16 float4 regs.
  {
    int kk = t;
    const float4* k4 =
        (const float4*)(k + ((size_t)(b * NL + c * CHUNK + kk) * NH + h) * ND);
    float4 kr[16];
#pragma unroll
    for (int j = 0; j < 16; j++) kr[j] = k4[j];
    for (int u = 0; u < NS; ++u) {
      float dot = 0.f;
#pragma unroll
      for (int j = 0; j < 16; j++) {
        float4 qq = QL4[u * 16 + j];  // broadcast read
        dot += qq.x * kr[j].x + qq.y * kr[j].y + qq.z * kr[j].z + qq.w * kr[j].w;
      }
      SLDS[u * 260 + kk] = dot * SCALE;
    }
  }
  __syncthreads();

  // Phase B2: per-row chunk softmax (max, exp, sum), exp written back.
  for (int u = wid; u < NS; u += 4) {
    float4 sv = *(const float4*)&SLDS[u * 260 + lane * 4];
    float mx = fmaxf(fmaxf(sv.x, sv.y), fmaxf(sv.z, sv.w));
#pragma unroll
    for (int off = 32; off; off >>= 1) mx = fmaxf(mx, __shfl_xor(mx, off));
    float e0 = expf(sv.x - mx), e1 = expf(sv.y - mx);
    float e2 = expf(sv.z - mx), e3 = expf(sv.w - mx);
    float s = e0 + e1 + e2 + e3;
#pragma unroll
    for (int off = 32; off; off >>= 1) s += __shfl_xor(s, off);
    *(float4*)&SLDS[u * 260 + lane * 4] = make_float4(e0, e1, e2, e3);
    if (lane == 0) { mcs[u] = mx; lcs[u] = s; }
  }
  __syncthreads();

  // Phase C: O_partial = P @ V_chunk. Wave w owns rows u = w+4i; lane = d.
  float acc[12];
#pragma unroll
  for (int i = 0; i < 12; i++) acc[i] = 0.f;
  const float* vbase = v + ((size_t)(b * NL + c * CHUNK) * NH + h) * ND + lane;
  for (int kb = 0; kb < 64; ++kb) {
    float vd0 = vbase[(size_t)(kb * 4 + 0) * NH * ND];
    float vd1 = vbase[(size_t)(kb * 4 + 1) * NH * ND];
    float vd2 = vbase[(size_t)(kb * 4 + 2) * NH * ND];
    float vd3 = vbase[(size_t)(kb * 4 + 3) * NH * ND];
#pragma unroll
    for (int i = 0; i < 12; i++) {
      int u = wid + 4 * i;
      if (u < NS) {
        float4 p4 = *(const float4*)&SLDS[u * 260 + kb * 4];  // broadcast
        acc[i] += p4.x * vd0 + p4.y * vd1 + p4.z * vd2 + p4.w * vd3;
      }
    }
  }
#pragma unroll
  for (int i = 0; i < 12; i++) {
    int u = wid + 4 * i;
    if (u < NS)
      op_out[(((size_t)bh * NCHUNK + c) * NS + u) * ND + lane] = acc[i];
  }
  if (t < NS) {
    mc_out[(bh * NCHUNK + c) * NS + t] = mcs[t];
    lc_out[(bh * NCHUNK + c) * NS + t] = lcs[t];
  }
}

// ---------------- K5: combine partials + scatter ----------------
__global__ __launch_bounds__(256) void k_combine(
    const float* __restrict__ mc, const float* __restrict__ lc,
    const float* __restrict__ op, const int* __restrict__ mtop,
    float* __restrict__ out)
{
  int gw = blockIdx.x * 4 + (threadIdx.x >> 6);  // 1440 waves
  int lane = threadIdx.x & 63;
  int bh = gw / NS, u = gw % NS;
  float M = neg_inf();
  for (int c = 0; c < NCHUNK; c++)
    M = fmaxf(M, mc[(bh * NCHUNK + c) * NS + u]);
  float Lsum = 0.f, O = 0.f;
  for (int c = 0; c < NCHUNK; c++) {
    float e = expf(mc[(bh * NCHUNK + c) * NS + u] - M);
    Lsum += lc[(bh * NCHUNK + c) * NS + u] * e;
    O += op[(((size_t)bh * NCHUNK + c) * NS + u) * ND + lane] * e;
  }
  int row = mtop[bh * NS + u];
  out[((size_t)bh * NL + row) * ND + lane] = O / Lsum;
}

extern "C" void kernel_launch(void* const* d_in, const int* in_sizes, int n_in,
                              void* d_out, int out_size, void* d_ws, size_t ws_size,
                              hipStream_t stream) {
  const float* q = (const float*)d_in[0];
  const float* k = (const float*)d_in[1];
  const float* v = (const float*)d_in[2];
  const int* idxs = (const int*)d_in[3];
  float* out = (float*)d_out;
  float* ws = (float*)d_ws;

  // workspace layout (floats): total ~1.66M floats = 6.62 MB
  float* m_ws  = ws;                    // 131072
  int*   mtop  = (int*)(ws + 131072);   // 1440 ints
  float* meanv = ws + 132512;           // 2048
  float* mc    = ws + 134560;           // 32*16*45 = 23040
  float* lc    = ws + 157600;           // 23040
  float* op    = ws + 180640;           // 32*16*45*64 = 1474560

  hipLaunchKernelGGL(k_compute_m, dim3(32768), dim3(256), 0, stream, q, k, idxs, m_ws);
  hipLaunchKernelGGL(k_topk,      dim3(32),    dim3(256), 0, stream, m_ws, mtop);
  hipLaunchKernelGGL(k_meanv,     dim3(32),    dim3(256), 0, stream, v, meanv);
  hipLaunchKernelGGL(k_fill,      dim3(2048),  dim3(256), 0, stream, meanv, (float4*)out);
  hipLaunchKernelGGL(k_scores,    dim3(512),   dim3(256), 0, stream, q, k, v, mtop, mc, lc, op);
  hipLaunchKernelGGL(k_combine,   dim3(360),   dim3(256), 0, stream, mc, lc, op, mtop, out);
}

// Round 2
// 415.484 us; speedup vs baseline: 1.6452x; 1.6452x over previous
//
#include <hip/hip_runtime.h>
#include <hip/hip_bf16.h>

// ProbAttention (Informer ProbSparse) on MI355X.
// Shapes: queries/keys/values (4, 4096, 8, 64) f32 in (b, l, h, d) layout.
// index_sample (4096, 45) int32. Output context (b, h, 4096, 64) f32.
//
// Pipeline (all fp32 — no fp32 MFMA on CDNA4; precision needed for top-k):
//   K1 compute_m   : m[b,h,l] = max_s(q.k_samp) - sum_s(q.k_samp)/4096
//   K2 topk        : per (b,h) top-45 indices of m (tie: lowest index)
//   K3a meanv_part : partial sums of v over l (2048 blocks, full chip)
//   K3b meanv_final: reduce 64 partials -> meanv
//   K3c fill       : out[...] = meanv broadcast (32 MB write)
//   K4 scores      : split-K flash: per (b,h, key-chunk of 256): partial
//                    softmax(Qr K^T * 0.125) and partial P@V -> ws
//   K5 combine     : merge 16 chunk partials, scatter to out rows m_top[u]

#define NB 4
#define NH 8
#define NL 4096
#define ND 64
#define NS 45          // U = n_top = 45
#define SCALE 0.125f   // 1/sqrt(64)
#define NCHUNK 16
#define CHUNK 256

static __device__ __forceinline__ float neg_inf() { return -__builtin_inff(); }

// ---------------- K1: sampled-dot m ----------------
// One wave per (b,h,l). Lane s < 45 computes dot(q[l], k[idx[l,s]]) over 64.
__global__ __launch_bounds__(256) void k_compute_m(
    const float* __restrict__ q, const float* __restrict__ k,
    const int* __restrict__ idxs, float* __restrict__ m_out)
{
  int gb = blockIdx.x;
  int xcd = gb & 7, seq = gb >> 3;          // XCD-locality swizzle: 4 bh per XCD
  int bh = xcd * 4 + (seq >> 10);
  int lblk = seq & 1023;
  int wid = threadIdx.x >> 6;
  int lane = threadIdx.x & 63;
  int b = bh >> 3, h = bh & 7;
  int l = lblk * 4 + wid;
  int s = (lane < NS) ? lane : 0;
  int ki = idxs[l * NS + s];
  const float4* q4 = (const float4*)(q + ((size_t)(b * NL + l) * NH + h) * ND);
  const float4* k4 = (const float4*)(k + ((size_t)(b * NL + ki) * NH + h) * ND);
  float dot = 0.f;
#pragma unroll
  for (int j = 0; j < 16; j++) {
    float4 qq = q4[j];  // uniform across wave -> broadcast
    float4 kk = k4[j];
    dot += qq.x * kk.x + qq.y * kk.y + qq.z * kk.z + qq.w * kk.w;
  }
  float mx = (lane < NS) ? dot : neg_inf();
  float sm = (lane < NS) ? dot : 0.f;
#pragma unroll
  for (int off = 32; off; off >>= 1) {
    mx = fmaxf(mx, __shfl_xor(mx, off));
    sm += __shfl_xor(sm, off);
  }
  if (lane == 0) m_out[bh * NL + l] = mx - sm * (1.0f / 4096.0f);
}

// ---------------- K2: top-45 per (b,h) ----------------
// Iterative argmax, 45 rounds. Tie-break: lower index wins (matches lax.top_k).
// Per-wave 64-bit shfl butterfly (no barrier) + 4-way LDS merge (2 barriers/it).
__global__ __launch_bounds__(256) void k_topk(
    const float* __restrict__ m_in, int* __restrict__ mtop)
{
  __shared__ float vals[NL];
  __shared__ unsigned long long wred[4];
  int bh = blockIdx.x;
  int t = threadIdx.x;
  int wid = t >> 6, lane = t & 63;
  for (int i = t; i < NL; i += 256) vals[i] = m_in[bh * NL + i];
  __syncthreads();
  for (int it = 0; it < NS; ++it) {
    unsigned long long best = 0ull;
    for (int i = t; i < NL; i += 256) {
      float v = vals[i];
      unsigned u = __float_as_uint(v);
      u ^= (u >> 31) ? 0xFFFFFFFFu : 0x80000000u;  // monotone mapping
      unsigned long long key =
          ((unsigned long long)u << 32) | (unsigned)(~(unsigned)i);
      if (key > best) best = key;
    }
#pragma unroll
    for (int off = 32; off; off >>= 1) {
      unsigned long long o = __shfl_xor(best, off);
      if (o > best) best = o;
    }
    if (lane == 0) wred[wid] = best;
    __syncthreads();
    if (t == 0) {
      unsigned long long b0 = wred[0];
      if (wred[1] > b0) b0 = wred[1];
      if (wred[2] > b0) b0 = wred[2];
      if (wred[3] > b0) b0 = wred[3];
      int idx = (int)(~(unsigned)(b0 & 0xFFFFFFFFull));
      mtop[bh * NS + it] = idx;
      vals[idx] = neg_inf();
    }
    __syncthreads();
  }
}

// ---------------- K3a: partial mean of v over l ----------------
// grid (32 bh, 64 chunks); block sums 64 consecutive l rows.
__global__ __launch_bounds__(256) void k_meanv_part(
    const float* __restrict__ v, float* __restrict__ vpart)
{
  __shared__ float part[4][ND];
  int bh = blockIdx.x, c = blockIdx.y;
  int b = bh >> 3, h = bh & 7;
  int t = threadIdx.x, d = t & 63, g = t >> 6;
  float a0 = 0.f, a1 = 0.f, a2 = 0.f, a3 = 0.f;
  const float* vb = v + ((size_t)(b * NL + c * 64) * NH + h) * ND + d;
#pragma unroll
  for (int i = 0; i < 4; i++) {
    a0 += vb[(size_t)(g + 4 * (4 * i + 0)) * NH * ND];
    a1 += vb[(size_t)(g + 4 * (4 * i + 1)) * NH * ND];
    a2 += vb[(size_t)(g + 4 * (4 * i + 2)) * NH * ND];
    a3 += vb[(size_t)(g + 4 * (4 * i + 3)) * NH * ND];
  }
  part[g][d] = (a0 + a1) + (a2 + a3);
  __syncthreads();
  if (g == 0) {
    float s = part[0][d] + part[1][d] + part[2][d] + part[3][d];
    vpart[(bh * 64 + c) * ND + d] = s;
  }
}

// ---------------- K3b: reduce partials -> meanv ----------------
__global__ __launch_bounds__(64) void k_meanv_final(
    const float* __restrict__ vpart, float* __restrict__ meanv)
{
  int bh = blockIdx.x, d = threadIdx.x;
  float s = 0.f;
  for (int c = 0; c < 64; c++) s += vpart[(bh * 64 + c) * ND + d];
  meanv[bh * ND + d] = s * (1.0f / 4096.0f);
}

// ---------------- K3c: fill output with meanv ----------------
__global__ __launch_bounds__(256) void k_fill(
    const float* __restrict__ meanv, float4* __restrict__ out4)
{
  const int total = NB * NH * NL * ND / 4;  // 2M float4
  const float4* mv4 = (const float4*)meanv;
  for (int i = blockIdx.x * 256 + threadIdx.x; i < total; i += gridDim.x * 256) {
    int bh = i >> 16;       // 65536 float4 per (b,h)
    int d4 = i & 15;
    out4[i] = mv4[bh * 16 + d4];
  }
}

// ---------------- K4: split-K scores+softmax+PV partials ----------------
// Block = (b,h, chunk of 256 keys), 256 threads (4 waves).
__global__ __launch_bounds__(256) void k_scores(
    const float* __restrict__ q, const float* __restrict__ k,
    const float* __restrict__ v, const int* __restrict__ mtop,
    float* __restrict__ mc_out, float* __restrict__ lc_out,
    float* __restrict__ op_out)
{
  __shared__ float QLDS[NS * ND];     // 45x64
  __shared__ float SLDS[NS * 260];    // 45 rows, 260-stride (pad), cols 0..255
  __shared__ int mt[NS];
  __shared__ float mcs[NS], lcs[NS];

  int gb = blockIdx.x;
  int xcd = gb & 7, seq = gb >> 3;    // 512 blocks: 4 bh per XCD
  int bh = xcd * 4 + (seq >> 4);
  int c = seq & 15;
  int b = bh >> 3, h = bh & 7;
  int t = threadIdx.x;
  int wid = t >> 6, lane = t & 63;

  if (t < NS) mt[t] = mtop[bh * NS + t];
  __syncthreads();

  // stage Qr (45 rows) into LDS
  const float4* q4 = (const float4*)q;
  float4* QL4 = (float4*)QLDS;
  for (int i = t; i < NS * 16; i += 256) {
    int u = i >> 4, j = i & 15;
    QL4[i] = q4[((size_t)(b * NL + mt[u]) * NH + h) * 16 + j];
  }
  __syncthreads();

  // Phase B: thread t owns key column kk=t; K row held in 16 float4 regs.
  {
    int kk = t;
    const float4* k4 =
        (const float4*)(k + ((size_t)(b * NL + c * CHUNK + kk) * NH + h) * ND);
    float4 kr[16];
#pragma unroll
    for (int j = 0; j < 16; j++) kr[j] = k4[j];
    for (int u = 0; u < NS; ++u) {
      float dot = 0.f;
#pragma unroll
      for (int j = 0; j < 16; j++) {
        float4 qq = QL4[u * 16 + j];  // broadcast read
        dot += qq.x * kr[j].x + qq.y * kr[j].y + qq.z * kr[j].z + qq.w * kr[j].w;
      }
      SLDS[u * 260 + kk] = dot * SCALE;
    }
  }
  __syncthreads();

  // Phase B2: per-row chunk softmax (max, exp, sum), exp written back.
  for (int u = wid; u < NS; u += 4) {
    float4 sv = *(const float4*)&SLDS[u * 260 + lane * 4];
    float mx = fmaxf(fmaxf(sv.x, sv.y), fmaxf(sv.z, sv.w));
#pragma unroll
    for (int off = 32; off; off >>= 1) mx = fmaxf(mx, __shfl_xor(mx, off));
    float e0 = expf(sv.x - mx), e1 = expf(sv.y - mx);
    float e2 = expf(sv.z - mx), e3 = expf(sv.w - mx);
    float s = e0 + e1 + e2 + e3;
#pragma unroll
    for (int off = 32; off; off >>= 1) s += __shfl_xor(s, off);
    *(float4*)&SLDS[u * 260 + lane * 4] = make_float4(e0, e1, e2, e3);
    if (lane == 0) { mcs[u] = mx; lcs[u] = s; }
  }
  __syncthreads();

  // Phase C: O_partial = P @ V_chunk. Wave w owns rows u = w+4i; lane = d.
  float acc[12];
#pragma unroll
  for (int i = 0; i < 12; i++) acc[i] = 0.f;
  const float* vbase = v + ((size_t)(b * NL + c * CHUNK) * NH + h) * ND + lane;
  for (int kb = 0; kb < 64; ++kb) {
    float vd0 = vbase[(size_t)(kb * 4 + 0) * NH * ND];
    float vd1 = vbase[(size_t)(kb * 4 + 1) * NH * ND];
    float vd2 = vbase[(size_t)(kb * 4 + 2) * NH * ND];
    float vd3 = vbase[(size_t)(kb * 4 + 3) * NH * ND];
#pragma unroll
    for (int i = 0; i < 12; i++) {
      int u = wid + 4 * i;
      if (u < NS) {
        float4 p4 = *(const float4*)&SLDS[u * 260 + kb * 4];  // broadcast
        acc[i] += p4.x * vd0 + p4.y * vd1 + p4.z * vd2 + p4.w * vd3;
      }
    }
  }
#pragma unroll
  for (int i = 0; i < 12; i++) {
    int u = wid + 4 * i;
    if (u < NS)
      op_out[(((size_t)bh * NCHUNK + c) * NS + u) * ND + lane] = acc[i];
  }
  if (t < NS) {
    mc_out[(bh * NCHUNK + c) * NS + t] = mcs[t];
    lc_out[(bh * NCHUNK + c) * NS + t] = lcs[t];
  }
}

// ---------------- K5: combine partials + scatter ----------------
__global__ __launch_bounds__(256) void k_combine(
    const float* __restrict__ mc, const float* __restrict__ lc,
    const float* __restrict__ op, const int* __restrict__ mtop,
    float* __restrict__ out)
{
  int gw = blockIdx.x * 4 + (threadIdx.x >> 6);  // 1440 waves
  int lane = threadIdx.x & 63;
  int bh = gw / NS, u = gw % NS;
  float M = neg_inf();
  for (int c = 0; c < NCHUNK; c++)
    M = fmaxf(M, mc[(bh * NCHUNK + c) * NS + u]);
  float Lsum = 0.f, O = 0.f;
  for (int c = 0; c < NCHUNK; c++) {
    float e = expf(mc[(bh * NCHUNK + c) * NS + u] - M);
    Lsum += lc[(bh * NCHUNK + c) * NS + u] * e;
    O += op[(((size_t)bh * NCHUNK + c) * NS + u) * ND + lane] * e;
  }
  int row = mtop[bh * NS + u];
  out[((size_t)bh * NL + row) * ND + lane] = O / Lsum;
}

extern "C" void kernel_launch(void* const* d_in, const int* in_sizes, int n_in,
                              void* d_out, int out_size, void* d_ws, size_t ws_size,
                              hipStream_t stream) {
  const float* q = (const float*)d_in[0];
  const float* k = (const float*)d_in[1];
  const float* v = (const float*)d_in[2];
  const int* idxs = (const int*)d_in[3];
  float* out = (float*)d_out;
  float* ws = (float*)d_ws;

  // workspace layout (floats): total ~1.66M floats = 6.62 MB
  float* m_ws  = ws;                    // 131072
  int*   mtop  = (int*)(ws + 131072);   // 1440 ints
  float* meanv = ws + 132512;           // 2048
  float* mc    = ws + 134560;           // 32*16*45 = 23040
  float* lc    = ws + 157600;           // 23040
  float* op    = ws + 180640;           // 32*16*45*64 = 1474560
  // vpart (32*64*64 = 131072 floats) aliases op: fully consumed by
  // k_meanv_final before k_scores writes op (same-stream ordering).
  float* vpart = op;

  hipLaunchKernelGGL(k_compute_m,   dim3(32768),     dim3(256), 0, stream, q, k, idxs, m_ws);
  hipLaunchKernelGGL(k_topk,        dim3(32),        dim3(256), 0, stream, m_ws, mtop);
  hipLaunchKernelGGL(k_meanv_part,  dim3(32, 64),    dim3(256), 0, stream, v, vpart);
  hipLaunchKernelGGL(k_meanv_final, dim3(32),        dim3(64),  0, stream, vpart, meanv);
  hipLaunchKernelGGL(k_fill,        dim3(2048),      dim3(256), 0, stream, meanv, (float4*)out);
  hipLaunchKernelGGL(k_scores,      dim3(512),       dim3(256), 0, stream, q, k, v, mtop, mc, lc, op);
  hipLaunchKernelGGL(k_combine,     dim3(360),       dim3(256), 0, stream, mc, lc, op, mtop, out);
}

// Round 3
// 270.626 us; speedup vs baseline: 2.5258x; 1.5353x over previous
//
#include <hip/hip_runtime.h>
#include <hip/hip_bf16.h>

// ProbAttention (Informer ProbSparse) on MI355X.
// Shapes: queries/keys/values (4, 4096, 8, 64) f32 in (b, l, h, d) layout.
// index_sample (4096, 45) int32. Output context (b, h, 4096, 64) f32.
//
// Pipeline (all fp32 — no fp32 MFMA on CDNA4; precision needed for top-k):
//   K1 compute_m   : m[b,h,l] = max_s(q.k_samp) - sum_s(q.k_samp)/4096
//                    block per (b,l), all 8 heads at once: sampled K block
//                    k[b,ki,:,:] is 2KB contiguous -> fully coalesced loads.
//   K2 topk        : per (b,h) top-45 indices of m (tie: lowest index)
//   K3a meanv_part : partial sums of v over l (2048 blocks, full chip)
//   K3b meanv_final: reduce 64 partials -> meanv
//   K3c fill       : out[...] = meanv broadcast (32 MB write)
//   K4 scores      : split-K flash: per (b,h, key-chunk of 256): partial
//                    softmax(Qr K^T * 0.125) and partial P@V -> ws
//   K5 combine     : merge 16 chunk partials, scatter to out rows m_top[u]

#define NB 4
#define NH 8
#define NL 4096
#define ND 64
#define NS 45          // U = n_top = 45
#define SCALE 0.125f   // 1/sqrt(64)
#define NCHUNK 16
#define CHUNK 256

static __device__ __forceinline__ float neg_inf() { return -__builtin_inff(); }

// ---------------- K1: sampled-dot m ----------------
// Block per (b,l), 256 threads = 4 waves. Wave w handles samples s = w+4j.
// Each sample: k[b,ki,:,:] = 2KB contiguous = 2 coalesced 1KB float4 loads.
// 16-lane group g computes dot for head g (low 1KB) and head 4+g (high 1KB).
__global__ __launch_bounds__(256) void k_compute_m(
    const float* __restrict__ q, const float* __restrict__ k,
    const int* __restrict__ idxs, float* __restrict__ m_out)
{
  __shared__ float lmx[4][NH], lsm[4][NH];
  int gb = blockIdx.x;                 // 16384 blocks
  int xcd = gb & 7;                    // XCD swizzle: b -> 2 XCDs (8MB K in 8MB L2)
  int b = xcd >> 1;
  int l = ((gb >> 3) << 1) | (xcd & 1);
  int t = threadIdx.x, w = t >> 6, lane = t & 63, g = lane >> 4;

  const float4* q4 = (const float4*)(q + (size_t)(b * NL + l) * NH * ND);
  float4 qa = q4[lane];        // head g,   dims (lane&15)*4..
  float4 qb = q4[64 + lane];   // head 4+g
  const float4* kb4 = (const float4*)(k + (size_t)b * NL * NH * ND);
  const int* irow = idxs + l * NS;

  int kis[12];
#pragma unroll
  for (int j = 0; j < 12; j++) {
    int s = w + 4 * j;
    kis[j] = (s < NS) ? irow[s] : 0;
  }

  float mxa = neg_inf(), sma = 0.f, mxb = neg_inf(), smb = 0.f;
#pragma unroll
  for (int j = 0; j < 12; j++) {
    int s = w + 4 * j;
    if (s < NS) {
      const float4* kk = kb4 + (size_t)kis[j] * 128;  // 2KB block
      float4 ka = kk[lane];
      float4 kb = kk[64 + lane];
      float pa = ka.x * qa.x + ka.y * qa.y + ka.z * qa.z + ka.w * qa.w;
      float pb = kb.x * qb.x + kb.y * qb.y + kb.z * qb.z + kb.w * qb.w;
#pragma unroll
      for (int off = 1; off < 16; off <<= 1) {
        pa += __shfl_xor(pa, off);
        pb += __shfl_xor(pb, off);
      }
      mxa = fmaxf(mxa, pa); sma += pa;
      mxb = fmaxf(mxb, pb); smb += pb;
    }
  }
  if ((lane & 15) == 0) {
    lmx[w][g] = mxa; lsm[w][g] = sma;
    lmx[w][4 + g] = mxb; lsm[w][4 + g] = smb;
  }
  __syncthreads();
  if (t < NH) {
    float mx = lmx[0][t], sm = lsm[0][t];
#pragma unroll
    for (int w2 = 1; w2 < 4; w2++) {
      mx = fmaxf(mx, lmx[w2][t]);
      sm += lsm[w2][t];
    }
    m_out[(b * NH + t) * NL + l] = mx - sm * (1.0f / 4096.0f);
  }
}

// ---------------- K2: top-45 per (b,h) ----------------
// Iterative argmax, 45 rounds. Tie-break: lower index wins (matches lax.top_k).
// Per-wave 64-bit shfl butterfly (no barrier) + 4-way LDS merge (2 barriers/it).
__global__ __launch_bounds__(256) void k_topk(
    const float* __restrict__ m_in, int* __restrict__ mtop)
{
  __shared__ float vals[NL];
  __shared__ unsigned long long wred[4];
  int bh = blockIdx.x;
  int t = threadIdx.x;
  int wid = t >> 6, lane = t & 63;
  for (int i = t; i < NL; i += 256) vals[i] = m_in[bh * NL + i];
  __syncthreads();
  for (int it = 0; it < NS; ++it) {
    unsigned long long best = 0ull;
    for (int i = t; i < NL; i += 256) {
      float v = vals[i];
      unsigned u = __float_as_uint(v);
      u ^= (u >> 31) ? 0xFFFFFFFFu : 0x80000000u;  // monotone mapping
      unsigned long long key =
          ((unsigned long long)u << 32) | (unsigned)(~(unsigned)i);
      if (key > best) best = key;
    }
#pragma unroll
    for (int off = 32; off; off >>= 1) {
      unsigned long long o = __shfl_xor(best, off);
      if (o > best) best = o;
    }
    if (lane == 0) wred[wid] = best;
    __syncthreads();
    if (t == 0) {
      unsigned long long b0 = wred[0];
      if (wred[1] > b0) b0 = wred[1];
      if (wred[2] > b0) b0 = wred[2];
      if (wred[3] > b0) b0 = wred[3];
      int idx = (int)(~(unsigned)(b0 & 0xFFFFFFFFull));
      mtop[bh * NS + it] = idx;
      vals[idx] = neg_inf();
    }
    __syncthreads();
  }
}

// ---------------- K3a: partial mean of v over l ----------------
// grid (32 bh, 64 chunks); block sums 64 consecutive l rows.
__global__ __launch_bounds__(256) void k_meanv_part(
    const float* __restrict__ v, float* __restrict__ vpart)
{
  __shared__ float part[4][ND];
  int bh = blockIdx.x, c = blockIdx.y;
  int b = bh >> 3, h = bh & 7;
  int t = threadIdx.x, d = t & 63, g = t >> 6;
  float a0 = 0.f, a1 = 0.f, a2 = 0.f, a3 = 0.f;
  const float* vb = v + ((size_t)(b * NL + c * 64) * NH + h) * ND + d;
#pragma unroll
  for (int i = 0; i < 4; i++) {
    a0 += vb[(size_t)(g + 4 * (4 * i + 0)) * NH * ND];
    a1 += vb[(size_t)(g + 4 * (4 * i + 1)) * NH * ND];
    a2 += vb[(size_t)(g + 4 * (4 * i + 2)) * NH * ND];
    a3 += vb[(size_t)(g + 4 * (4 * i + 3)) * NH * ND];
  }
  part[g][d] = (a0 + a1) + (a2 + a3);
  __syncthreads();
  if (g == 0) {
    float s = part[0][d] + part[1][d] + part[2][d] + part[3][d];
    vpart[(bh * 64 + c) * ND + d] = s;
  }
}

// ---------------- K3b: reduce partials -> meanv ----------------
__global__ __launch_bounds__(64) void k_meanv_final(
    const float* __restrict__ vpart, float* __restrict__ meanv)
{
  int bh = blockIdx.x, d = threadIdx.x;
  float s = 0.f;
  for (int c = 0; c < 64; c++) s += vpart[(bh * 64 + c) * ND + d];
  meanv[bh * ND + d] = s * (1.0f / 4096.0f);
}

// ---------------- K3c: fill output with meanv ----------------
__global__ __launch_bounds__(256) void k_fill(
    const float* __restrict__ meanv, float4* __restrict__ out4)
{
  const int total = NB * NH * NL * ND / 4;  // 2M float4
  const float4* mv4 = (const float4*)meanv;
  for (int i = blockIdx.x * 256 + threadIdx.x; i < total; i += gridDim.x * 256) {
    int bh = i >> 16;       // 65536 float4 per (b,h)
    int d4 = i & 15;
    out4[i] = mv4[bh * 16 + d4];
  }
}

// ---------------- K4: split-K scores+softmax+PV partials ----------------
// Block = (b,h, chunk of 256 keys), 256 threads (4 waves).
__global__ __launch_bounds__(256) void k_scores(
    const float* __restrict__ q, const float* __restrict__ k,
    const float* __restrict__ v, const int* __restrict__ mtop,
    float* __restrict__ mc_out, float* __restrict__ lc_out,
    float* __restrict__ op_out)
{
  __shared__ float QLDS[NS * ND];     // 45x64
  __shared__ float SLDS[NS * 260];    // 45 rows, 260-stride (pad), cols 0..255
  __shared__ int mt[NS];
  __shared__ float mcs[NS], lcs[NS];

  int gb = blockIdx.x;
  int xcd = gb & 7, seq = gb >> 3;    // 512 blocks: 4 bh per XCD
  int bh = xcd * 4 + (seq >> 4);
  int c = seq & 15;
  int b = bh >> 3, h = bh & 7;
  int t = threadIdx.x;
  int wid = t >> 6, lane = t & 63;

  if (t < NS) mt[t] = mtop[bh * NS + t];
  __syncthreads();

  // stage Qr (45 rows) into LDS
  const float4* q4 = (const float4*)q;
  float4* QL4 = (float4*)QLDS;
  for (int i = t; i < NS * 16; i += 256) {
    int u = i >> 4, j = i & 15;
    QL4[i] = q4[((size_t)(b * NL + mt[u]) * NH + h) * 16 + j];
  }
  __syncthreads();

  // Phase B: thread t owns key column kk=t; K row held in 16 float4 regs.
  {
    int kk = t;
    const float4* k4 =
        (const float4*)(k + ((size_t)(b * NL + c * CHUNK + kk) * NH + h) * ND);
    float4 kr[16];
#pragma unroll
    for (int j = 0; j < 16; j++) kr[j] = k4[j];
    for (int u = 0; u < NS; ++u) {
      float dot = 0.f;
#pragma unroll
      for (int j = 0; j < 16; j++) {
        float4 qq = QL4[u * 16 + j];  // broadcast read
        dot += qq.x * kr[j].x + qq.y * kr[j].y + qq.z * kr[j].z + qq.w * kr[j].w;
      }
      SLDS[u * 260 + kk] = dot * SCALE;
    }
  }
  __syncthreads();

  // Phase B2: per-row chunk softmax (max, exp, sum), exp written back.
  for (int u = wid; u < NS; u += 4) {
    float4 sv = *(const float4*)&SLDS[u * 260 + lane * 4];
    float mx = fmaxf(fmaxf(sv.x, sv.y), fmaxf(sv.z, sv.w));
#pragma unroll
    for (int off = 32; off; off >>= 1) mx = fmaxf(mx, __shfl_xor(mx, off));
    float e0 = expf(sv.x - mx), e1 = expf(sv.y - mx);
    float e2 = expf(sv.z - mx), e3 = expf(sv.w - mx);
    float s = e0 + e1 + e2 + e3;
#pragma unroll
    for (int off = 32; off; off >>= 1) s += __shfl_xor(s, off);
    *(float4*)&SLDS[u * 260 + lane * 4] = make_float4(e0, e1, e2, e3);
    if (lane == 0) { mcs[u] = mx; lcs[u] = s; }
  }
  __syncthreads();

  // Phase C: O_partial = P @ V_chunk. Wave w owns rows u = w+4i; lane = d.
  float acc[12];
#pragma unroll
  for (int i = 0; i < 12; i++) acc[i] = 0.f;
  const float* vbase = v + ((size_t)(b * NL + c * CHUNK) * NH + h) * ND + lane;
  for (int kb = 0; kb < 64; ++kb) {
    float vd0 = vbase[(size_t)(kb * 4 + 0) * NH * ND];
    float vd1 = vbase[(size_t)(kb * 4 + 1) * NH * ND];
    float vd2 = vbase[(size_t)(kb * 4 + 2) * NH * ND];
    float vd3 = vbase[(size_t)(kb * 4 + 3) * NH * ND];
#pragma unroll
    for (int i = 0; i < 12; i++) {
      int u = wid + 4 * i;
      if (u < NS) {
        float4 p4 = *(const float4*)&SLDS[u * 260 + kb * 4];  // broadcast
        acc[i] += p4.x * vd0 + p4.y * vd1 + p4.z * vd2 + p4.w * vd3;
      }
    }
  }
#pragma unroll
  for (int i = 0; i < 12; i++) {
    int u = wid + 4 * i;
    if (u < NS)
      op_out[(((size_t)bh * NCHUNK + c) * NS + u) * ND + lane] = acc[i];
  }
  if (t < NS) {
    mc_out[(bh * NCHUNK + c) * NS + t] = mcs[t];
    lc_out[(bh * NCHUNK + c) * NS + t] = lcs[t];
  }
}

// ---------------- K5: combine partials + scatter ----------------
__global__ __launch_bounds__(256) void k_combine(
    const float* __restrict__ mc, const float* __restrict__ lc,
    const float* __restrict__ op, const int* __restrict__ mtop,
    float* __restrict__ out)
{
  int gw = blockIdx.x * 4 + (threadIdx.x >> 6);  // 1440 waves
  int lane = threadIdx.x & 63;
  int bh = gw / NS, u = gw % NS;
  float M = neg_inf();
  for (int c = 0; c < NCHUNK; c++)
    M = fmaxf(M, mc[(bh * NCHUNK + c) * NS + u]);
  float Lsum = 0.f, O = 0.f;
  for (int c = 0; c < NCHUNK; c++) {
    float e = expf(mc[(bh * NCHUNK + c) * NS + u] - M);
    Lsum += lc[(bh * NCHUNK + c) * NS + u] * e;
    O += op[(((size_t)bh * NCHUNK + c) * NS + u) * ND + lane] * e;
  }
  int row = mtop[bh * NS + u];
  out[((size_t)bh * NL + row) * ND + lane] = O / Lsum;
}

extern "C" void kernel_launch(void* const* d_in, const int* in_sizes, int n_in,
                              void* d_out, int out_size, void* d_ws, size_t ws_size,
                              hipStream_t stream) {
  const float* q = (const float*)d_in[0];
  const float* k = (const float*)d_in[1];
  const float* v = (const float*)d_in[2];
  const int* idxs = (const int*)d_in[3];
  float* out = (float*)d_out;
  float* ws = (float*)d_ws;

  // workspace layout (floats): total ~1.66M floats = 6.62 MB
  float* m_ws  = ws;                    // 131072
  int*   mtop  = (int*)(ws + 131072);   // 1440 ints
  float* meanv = ws + 132512;           // 2048
  float* mc    = ws + 134560;           // 32*16*45 = 23040
  float* lc    = ws + 157600;           // 23040
  float* op    = ws + 180640;           // 32*16*45*64 = 1474560
  // vpart (32*64*64 = 131072 floats) aliases op: fully consumed by
  // k_meanv_final before k_scores writes op (same-stream ordering).
  float* vpart = op;

  hipLaunchKernelGGL(k_compute_m,   dim3(16384),     dim3(256), 0, stream, q, k, idxs, m_ws);
  hipLaunchKernelGGL(k_topk,        dim3(32),        dim3(256), 0, stream, m_ws, mtop);
  hipLaunchKernelGGL(k_meanv_part,  dim3(32, 64),    dim3(256), 0, stream, v, vpart);
  hipLaunchKernelGGL(k_meanv_final, dim3(32),        dim3(64),  0, stream, vpart, meanv);
  hipLaunchKernelGGL(k_fill,        dim3(2048),      dim3(256), 0, stream, meanv, (float4*)out);
  hipLaunchKernelGGL(k_scores,      dim3(512),       dim3(256), 0, stream, q, k, v, mtop, mc, lc, op);
  hipLaunchKernelGGL(k_combine,     dim3(360),       dim3(256), 0, stream, mc, lc, op, mtop, out);
}

// Round 5
// 230.510 us; speedup vs baseline: 2.9654x; 1.1740x over previous
//
#include <hip/hip_runtime.h>
#include <hip/hip_bf16.h>

// ProbAttention (Informer ProbSparse) on MI355X.
// Shapes: queries/keys/values (4, 4096, 8, 64) f32 in (b, l, h, d) layout.
// index_sample (4096, 45) int32. Output context (b, h, 4096, 64) f32.
//
// Pipeline (all fp32 — no fp32 MFMA on CDNA4; precision needed for top-k):
//   K1 compute_m   : m[b,h,l] = max_s(q.k_samp) - sum_s(q.k_samp)/4096
//                    block per (b,hg,l-grp): gather works on 1KB half-blocks
//                    k[b,ki,hg*4:(hg+1)*4,:]; (b,hg)->XCD so the 4MB gather
//                    working set is L2-resident. Q read non-temporally.
//   K2 topk        : per (b,h) top-45 indices of m (tie: lowest index)
//   K3a meanv_part : partial sums of v over l (2048 blocks, full chip)
//   K3b meanv_final: reduce 64 partials -> meanv
//   K3c fill       : out[...] = meanv broadcast (32 MB write)
//   K4 scores      : split-K flash: per (b,h, key-chunk of 256): partial
//                    softmax(Qr K^T * 0.125) and partial P@V -> ws
//   K5 combine     : merge 16 chunk partials, scatter to out rows m_top[u]

#define NB 4
#define NH 8
#define NL 4096
#define ND 64
#define NS 45          // U = n_top = 45
#define SCALE 0.125f   // 1/sqrt(64)
#define NCHUNK 16
#define CHUNK 256

typedef float floatx4 __attribute__((ext_vector_type(4)));

static __device__ __forceinline__ float neg_inf() { return -__builtin_inff(); }

// ---------------- K1: sampled-dot m ----------------
// Block per (b, hg, l-group of 4). Wave w = one l. 16-lane group g = head hg*4+g.
// Per sample: 1KB contiguous K half-block (64 lanes x float4), fully coalesced,
// L2-resident (4MB working set per (b,hg) pinned to one XCD via blockIdx&7).
__global__ __launch_bounds__(256) void k_compute_m(
    const float* __restrict__ q, const float* __restrict__ k,
    const int* __restrict__ idxs, float* __restrict__ m_out)
{
  __shared__ int sidx[4][NS];
  int gb = blockIdx.x;                 // 8192 blocks
  int pair = gb & 7;                   // (b,hg) -> XCD (round-robin dispatch)
  int b = pair >> 1, hg = pair & 1;
  int lg = gb >> 3;                    // 0..1023
  int t = threadIdx.x, w = t >> 6, lane = t & 63, g = lane >> 4;
  int l = lg * 4 + w;

  if (lane < NS) sidx[w][lane] = idxs[l * NS + lane];

  // Q: heads hg*4..hg*4+3 of row l, 1KB contiguous. Non-temporal (stream once,
  // don't evict the L2-resident K set).
  const floatx4* q4 =
      (const floatx4*)(q + ((size_t)(b * NL + l) * NH + hg * 4) * ND);
  floatx4 qr = __builtin_nontemporal_load(q4 + lane);

  // K half-block base for this (b,hg): row ki at +ki*128 float4s, 1KB each.
  const floatx4* kb4 = (const floatx4*)k + ((size_t)b * NL * NH + hg * 4) * 16;

  __syncthreads();

  float mx = neg_inf(), sm = 0.f;
#pragma unroll 5
  for (int s = 0; s < NS; ++s) {
    int ki = sidx[w][s];
    floatx4 kk = kb4[(size_t)ki * 128 + lane];
    float p = kk.x * qr.x + kk.y * qr.y + kk.z * qr.z + kk.w * qr.w;
#pragma unroll
    for (int off = 1; off < 16; off <<= 1) p += __shfl_xor(p, off);
    mx = fmaxf(mx, p);
    sm += p;
  }
  if ((lane & 15) == 0)
    m_out[((size_t)b * NH + hg * 4 + g) * NL + l] = mx - sm * (1.0f / 4096.0f);
}

// ---------------- K2: top-45 per (b,h) ----------------
// Iterative argmax, 45 rounds. Tie-break: lower index wins (matches lax.top_k).
// Per-wave 64-bit shfl butterfly (no barrier) + 4-way LDS merge (2 barriers/it).
__global__ __launch_bounds__(256) void k_topk(
    const float* __restrict__ m_in, int* __restrict__ mtop)
{
  __shared__ float vals[NL];
  __shared__ unsigned long long wred[4];
  int bh = blockIdx.x;
  int t = threadIdx.x;
  int wid = t >> 6, lane = t & 63;
  for (int i = t; i < NL; i += 256) vals[i] = m_in[bh * NL + i];
  __syncthreads();
  for (int it = 0; it < NS; ++it) {
    unsigned long long best = 0ull;
    for (int i = t; i < NL; i += 256) {
      float v = vals[i];
      unsigned u = __float_as_uint(v);
      u ^= (u >> 31) ? 0xFFFFFFFFu : 0x80000000u;  // monotone mapping
      unsigned long long key =
          ((unsigned long long)u << 32) | (unsigned)(~(unsigned)i);
      if (key > best) best = key;
    }
#pragma unroll
    for (int off = 32; off; off >>= 1) {
      unsigned long long o = __shfl_xor(best, off);
      if (o > best) best = o;
    }
    if (lane == 0) wred[wid] = best;
    __syncthreads();
    if (t == 0) {
      unsigned long long b0 = wred[0];
      if (wred[1] > b0) b0 = wred[1];
      if (wred[2] > b0) b0 = wred[2];
      if (wred[3] > b0) b0 = wred[3];
      int idx = (int)(~(unsigned)(b0 & 0xFFFFFFFFull));
      mtop[bh * NS + it] = idx;
      vals[idx] = neg_inf();
    }
    __syncthreads();
  }
}

// ---------------- K3a: partial mean of v over l ----------------
// grid (32 bh, 64 chunks); block sums 64 consecutive l rows.
__global__ __launch_bounds__(256) void k_meanv_part(
    const float* __restrict__ v, float* __restrict__ vpart)
{
  __shared__ float part[4][ND];
  int bh = blockIdx.x, c = blockIdx.y;
  int b = bh >> 3, h = bh & 7;
  int t = threadIdx.x, d = t & 63, g = t >> 6;
  float a0 = 0.f, a1 = 0.f, a2 = 0.f, a3 = 0.f;
  const float* vb = v + ((size_t)(b * NL + c * 64) * NH + h) * ND + d;
#pragma unroll
  for (int i = 0; i < 4; i++) {
    a0 += vb[(size_t)(g + 4 * (4 * i + 0)) * NH * ND];
    a1 += vb[(size_t)(g + 4 * (4 * i + 1)) * NH * ND];
    a2 += vb[(size_t)(g + 4 * (4 * i + 2)) * NH * ND];
    a3 += vb[(size_t)(g + 4 * (4 * i + 3)) * NH * ND];
  }
  part[g][d] = (a0 + a1) + (a2 + a3);
  __syncthreads();
  if (g == 0) {
    float s = part[0][d] + part[1][d] + part[2][d] + part[3][d];
    vpart[(bh * 64 + c) * ND + d] = s;
  }
}

// ---------------- K3b: reduce partials -> meanv ----------------
__global__ __launch_bounds__(64) void k_meanv_final(
    const float* __restrict__ vpart, float* __restrict__ meanv)
{
  int bh = blockIdx.x, d = threadIdx.x;
  float s = 0.f;
  for (int c = 0; c < 64; c++) s += vpart[(bh * 64 + c) * ND + d];
  meanv[bh * ND + d] = s * (1.0f / 4096.0f);
}

// ---------------- K3c: fill output with meanv ----------------
__global__ __launch_bounds__(256) void k_fill(
    const float* __restrict__ meanv, float4* __restrict__ out4)
{
  const int total = NB * NH * NL * ND / 4;  // 2M float4
  const float4* mv4 = (const float4*)meanv;
  for (int i = blockIdx.x * 256 + threadIdx.x; i < total; i += gridDim.x * 256) {
    int bh = i >> 16;       // 65536 float4 per (b,h)
    int d4 = i & 15;
    out4[i] = mv4[bh * 16 + d4];
  }
}

// ---------------- K4: split-K scores+softmax+PV partials ----------------
// Block = (b,h, chunk of 256 keys), 256 threads (4 waves).
__global__ __launch_bounds__(256) void k_scores(
    const float* __restrict__ q, const float* __restrict__ k,
    const float* __restrict__ v, const int* __restrict__ mtop,
    float* __restrict__ mc_out, float* __restrict__ lc_out,
    float* __restrict__ op_out)
{
  __shared__ float QLDS[NS * ND];     // 45x64
  __shared__ float SLDS[NS * 260];    // 45 rows, 260-stride (pad), cols 0..255
  __shared__ int mt[NS];
  __shared__ float mcs[NS], lcs[NS];

  int gb = blockIdx.x;
  int xcd = gb & 7, seq = gb >> 3;    // 512 blocks: 4 bh per XCD
  int bh = xcd * 4 + (seq >> 4);
  int c = seq & 15;
  int b = bh >> 3, h = bh & 7;
  int t = threadIdx.x;
  int wid = t >> 6, lane = t & 63;

  if (t < NS) mt[t] = mtop[bh * NS + t];
  __syncthreads();

  // stage Qr (45 rows) into LDS
  const float4* q4 = (const float4*)q;
  float4* QL4 = (float4*)QLDS;
  for (int i = t; i < NS * 16; i += 256) {
    int u = i >> 4, j = i & 15;
    QL4[i] = q4[((size_t)(b * NL + mt[u]) * NH + h) * 16 + j];
  }
  __syncthreads();

  // Phase B: thread t owns key column kk=t; K row held in 16 float4 regs.
  {
    int kk = t;
    const float4* k4 =
        (const float4*)(k + ((size_t)(b * NL + c * CHUNK + kk) * NH + h) * ND);
    float4 kr[16];
#pragma unroll
    for (int j = 0; j < 16; j++) kr[j] = k4[j];
    for (int u = 0; u < NS; ++u) {
      float dot = 0.f;
#pragma unroll
      for (int j = 0; j < 16; j++) {
        float4 qq = QL4[u * 16 + j];  // broadcast read
        dot += qq.x * kr[j].x + qq.y * kr[j].y + qq.z * kr[j].z + qq.w * kr[j].w;
      }
      SLDS[u * 260 + kk] = dot * SCALE;
    }
  }
  __syncthreads();

  // Phase B2: per-row chunk softmax (max, exp, sum), exp written back.
  for (int u = wid; u < NS; u += 4) {
    float4 sv = *(const float4*)&SLDS[u * 260 + lane * 4];
    float mx = fmaxf(fmaxf(sv.x, sv.y), fmaxf(sv.z, sv.w));
#pragma unroll
    for (int off = 32; off; off >>= 1) mx = fmaxf(mx, __shfl_xor(mx, off));
    float e0 = expf(sv.x - mx), e1 = expf(sv.y - mx);
    float e2 = expf(sv.z - mx), e3 = expf(sv.w - mx);
    float s = e0 + e1 + e2 + e3;
#pragma unroll
    for (int off = 32; off; off >>= 1) s += __shfl_xor(s, off);
    *(float4*)&SLDS[u * 260 + lane * 4] = make_float4(e0, e1, e2, e3);
    if (lane == 0) { mcs[u] = mx; lcs[u] = s; }
  }
  __syncthreads();

  // Phase C: O_partial = P @ V_chunk. Wave w owns rows u = w+4i; lane = d.
  float acc[12];
#pragma unroll
  for (int i = 0; i < 12; i++) acc[i] = 0.f;
  const float* vbase = v + ((size_t)(b * NL + c * CHUNK) * NH + h) * ND + lane;
  for (int kb = 0; kb < 64; ++kb) {
    float vd0 = vbase[(size_t)(kb * 4 + 0) * NH * ND];
    float vd1 = vbase[(size_t)(kb * 4 + 1) * NH * ND];
    float vd2 = vbase[(size_t)(kb * 4 + 2) * NH * ND];
    float vd3 = vbase[(size_t)(kb * 4 + 3) * NH * ND];
#pragma unroll
    for (int i = 0; i < 12; i++) {
      int u = wid + 4 * i;
      if (u < NS) {
        float4 p4 = *(const float4*)&SLDS[u * 260 + kb * 4];  // broadcast
        acc[i] += p4.x * vd0 + p4.y * vd1 + p4.z * vd2 + p4.w * vd3;
      }
    }
  }
#pragma unroll
  for (int i = 0; i < 12; i++) {
    int u = wid + 4 * i;
    if (u < NS)
      op_out[(((size_t)bh * NCHUNK + c) * NS + u) * ND + lane] = acc[i];
  }
  if (t < NS) {
    mc_out[(bh * NCHUNK + c) * NS + t] = mcs[t];
    lc_out[(bh * NCHUNK + c) * NS + t] = lcs[t];
  }
}

// ---------------- K5: combine partials + scatter ----------------
__global__ __launch_bounds__(256) void k_combine(
    const float* __restrict__ mc, const float* __restrict__ lc,
    const float* __restrict__ op, const int* __restrict__ mtop,
    float* __restrict__ out)
{
  int gw = blockIdx.x * 4 + (threadIdx.x >> 6);  // 1440 waves
  int lane = threadIdx.x & 63;
  int bh = gw / NS, u = gw % NS;
  float M = neg_inf();
  for (int c = 0; c < NCHUNK; c++)
    M = fmaxf(M, mc[(bh * NCHUNK + c) * NS + u]);
  float Lsum = 0.f, O = 0.f;
  for (int c = 0; c < NCHUNK; c++) {
    float e = expf(mc[(bh * NCHUNK + c) * NS + u] - M);
    Lsum += lc[(bh * NCHUNK + c) * NS + u] * e;
    O += op[(((size_t)bh * NCHUNK + c) * NS + u) * ND + lane] * e;
  }
  int row = mtop[bh * NS + u];
  out[((size_t)bh * NL + row) * ND + lane] = O / Lsum;
}

extern "C" void kernel_launch(void* const* d_in, const int* in_sizes, int n_in,
                              void* d_out, int out_size, void* d_ws, size_t ws_size,
                              hipStream_t stream) {
  const float* q = (const float*)d_in[0];
  const float* k = (const float*)d_in[1];
  const float* v = (const float*)d_in[2];
  const int* idxs = (const int*)d_in[3];
  float* out = (float*)d_out;
  float* ws = (float*)d_ws;

  // workspace layout (floats): total ~1.66M floats = 6.62 MB
  float* m_ws  = ws;                    // 131072
  int*   mtop  = (int*)(ws + 131072);   // 1440 ints
  float* meanv = ws + 132512;           // 2048
  float* mc    = ws + 134560;           // 32*16*45 = 23040
  float* lc    = ws + 157600;           // 23040
  float* op    = ws + 180640;           // 32*16*45*64 = 1474560
  // vpart (32*64*64 = 131072 floats) aliases op: fully consumed by
  // k_meanv_final before k_scores writes op (same-stream ordering).
  float* vpart = op;

  hipLaunchKernelGGL(k_compute_m,   dim3(8192),      dim3(256), 0, stream, q, k, idxs, m_ws);
  hipLaunchKernelGGL(k_topk,        dim3(32),        dim3(256), 0, stream, m_ws, mtop);
  hipLaunchKernelGGL(k_meanv_part,  dim3(32, 64),    dim3(256), 0, stream, v, vpart);
  hipLaunchKernelGGL(k_meanv_final, dim3(32),        dim3(64),  0, stream, vpart, meanv);
  hipLaunchKernelGGL(k_fill,        dim3(2048),      dim3(256), 0, stream, meanv, (float4*)out);
  hipLaunchKernelGGL(k_scores,      dim3(512),       dim3(256), 0, stream, q, k, v, mtop, mc, lc, op);
  hipLaunchKernelGGL(k_combine,     dim3(360),       dim3(256), 0, stream, mc, lc, op, mtop, out);
}

// Round 6
// 206.194 us; speedup vs baseline: 3.3151x; 1.1179x over previous
//
#include <hip/hip_runtime.h>
#include <hip/hip_bf16.h>

// ProbAttention (Informer ProbSparse) on MI355X.
// Shapes: queries/keys/values (4, 4096, 8, 64) f32 in (b, l, h, d) layout.
// index_sample (4096, 45) int32. Output context (b, h, 4096, 64) f32.
//
// Pipeline (all fp32 — no fp32 MFMA on CDNA4; precision needed for top-k):
//   K1 compute_m   : m[b,h,l] = max_s(q.k_samp) - sum_s(q.k_samp)/4096
//                    block per (b,hg,l-grp): 1KB half-block gather, (b,hg)->XCD
//                    so the 4MB working set is L2-resident. 16-lane dot-reduce
//                    via DPP (VALU pipe), not shfl (DS pipe).
//   K2a topk_p1    : per (b,h,512-slice) top-45 candidates (packed u64 keys)
//   K2b topk_p2    : merge 8x45 candidates -> global top-45 (tie: lowest idx)
//   K3a meanv_part : partial sums of v over l (2048 blocks, full chip)
//   K3b meanv_final: reduce 64 partials -> meanv
//   K3c fill       : out[...] = meanv broadcast (32 MB write)
//   K4 scores      : split-K flash: per (b,h, key-chunk of 256): partial
//                    softmax(Qr K^T * 0.125) and partial P@V -> ws
//   K5 combine     : merge 16 chunk partials, scatter to out rows m_top[u]

#define NB 4
#define NH 8
#define NL 4096
#define ND 64
#define NS 45          // U = n_top = 45
#define SCALE 0.125f   // 1/sqrt(64)
#define NCHUNK 16
#define CHUNK 256

typedef float floatx4 __attribute__((ext_vector_type(4)));

static __device__ __forceinline__ float neg_inf() { return -__builtin_inff(); }

// VALU-pipe cross-lane add via DPP (no DS traffic).
template <int CTRL>
static __device__ __forceinline__ float dpp_add(float x) {
  int y = __builtin_amdgcn_update_dpp(0, __builtin_bit_cast(int, x), CTRL,
                                      0xF, 0xF, true);
  return x + __builtin_bit_cast(float, y);
}
// Sum over 16 contiguous lanes; every lane ends with the group total.
static __device__ __forceinline__ float red16(float x) {
  x = dpp_add<0x140>(x);  // row_mirror      (fold 16 -> 8)
  x = dpp_add<0x141>(x);  // row_half_mirror (fold 8 -> 4)
  x = dpp_add<0x4E>(x);   // quad_perm [2,3,0,1] = xor2
  x = dpp_add<0xB1>(x);   // quad_perm [1,0,3,2] = xor1
  return x;
}

// ---------------- K1: sampled-dot m ----------------
// Block per (b, hg, l-group of 4). Wave w = one l. 16-lane group g = head hg*4+g.
// Per sample: 1KB contiguous K half-block (64 lanes x float4), fully coalesced,
// L2-resident (4MB working set per (b,hg) pinned to one XCD via blockIdx&7).
__global__ __launch_bounds__(256) void k_compute_m(
    const float* __restrict__ q, const float* __restrict__ k,
    const int* __restrict__ idxs, float* __restrict__ m_out)
{
  __shared__ int sidx[4][NS];
  int gb = blockIdx.x;                 // 8192 blocks
  int pair = gb & 7;                   // (b,hg) -> XCD (round-robin dispatch)
  int b = pair >> 1, hg = pair & 1;
  int lg = gb >> 3;                    // 0..1023
  int t = threadIdx.x, w = t >> 6, lane = t & 63, g = lane >> 4;
  int l = lg * 4 + w;

  if (lane < NS) sidx[w][lane] = idxs[l * NS + lane];  // wave-private row

  // Q: heads hg*4..hg*4+3 of row l, 1KB contiguous. Non-temporal (stream once,
  // don't evict the L2-resident K set).
  const floatx4* q4 =
      (const floatx4*)(q + ((size_t)(b * NL + l) * NH + hg * 4) * ND);
  floatx4 qr = __builtin_nontemporal_load(q4 + lane);

  // K half-block base for this (b,hg): row ki at +ki*128 float4s, 1KB each.
  const floatx4* kb4 = (const floatx4*)k + ((size_t)b * NL * NH + hg * 4) * 16;

  float mx = neg_inf(), sm = 0.f;
#pragma unroll 5
  for (int s = 0; s < NS; ++s) {
    int ki = sidx[w][s];
    floatx4 kk = kb4[(size_t)ki * 128 + lane];
    float p = kk.x * qr.x + kk.y * qr.y + kk.z * qr.z + kk.w * qr.w;
    p = red16(p);                      // 16-lane dot, VALU-only
    mx = fmaxf(mx, p);
    sm += p;
  }
  if ((lane & 15) == 0)
    m_out[((size_t)b * NH + hg * 4 + g) * NL + l] = mx - sm * (1.0f / 4096.0f);
}

// ---------------- K2a: per-slice top-45 candidates ----------------
// Block = (bh, 512-slice). Keys: monotone(float) || ~index (exact tie-break).
__global__ __launch_bounds__(256) void k_topk_p1(
    const float* __restrict__ m_in, unsigned long long* __restrict__ cand)
{
  __shared__ unsigned long long keys[512];
  __shared__ unsigned long long wred[4];
  int blk = blockIdx.x;                // bh*8 + slice
  int bh = blk >> 3, slice = blk & 7;
  int t = threadIdx.x, wid = t >> 6, lane = t & 63;
  int base = slice * 512;
  for (int i = t; i < 512; i += 256) {
    float v = m_in[bh * NL + base + i];
    unsigned u = __float_as_uint(v);
    u ^= (u >> 31) ? 0xFFFFFFFFu : 0x80000000u;  // monotone mapping
    keys[i] = ((unsigned long long)u << 32) | (unsigned)(~(unsigned)(base + i));
  }
  __syncthreads();
  for (int it = 0; it < NS; ++it) {
    unsigned long long k0 = keys[t], k1 = keys[t + 256];
    unsigned long long best = k0 > k1 ? k0 : k1;
#pragma unroll
    for (int off = 32; off; off >>= 1) {
      unsigned long long o = __shfl_xor(best, off);
      if (o > best) best = o;
    }
    if (lane == 0) wred[wid] = best;
    __syncthreads();
    if (t == 0) {
      unsigned long long b0 = wred[0];
      if (wred[1] > b0) b0 = wred[1];
      if (wred[2] > b0) b0 = wred[2];
      if (wred[3] > b0) b0 = wred[3];
      cand[blk * NS + it] = b0;
      int gi = (int)(~(unsigned)(b0 & 0xFFFFFFFFull));
      keys[gi - base] = 0;
    }
    __syncthreads();
  }
}

// ---------------- K2b: merge 8x45 candidates -> top-45 ----------------
__global__ __launch_bounds__(256) void k_topk_p2(
    const unsigned long long* __restrict__ cand, int* __restrict__ mtop)
{
  __shared__ unsigned long long keys[8 * NS];  // 360
  __shared__ unsigned long long wred[4];
  __shared__ unsigned long long sbest;
  int bh = blockIdx.x;
  int t = threadIdx.x, wid = t >> 6, lane = t & 63;
  for (int i = t; i < 8 * NS; i += 256) keys[i] = cand[bh * 8 * NS + i];
  __syncthreads();
  for (int it = 0; it < NS; ++it) {
    unsigned long long best = (t < 8 * NS) ? keys[t] : 0ull;
    if (t + 256 < 8 * NS) {
      unsigned long long k1 = keys[t + 256];
      if (k1 > best) best = k1;
    }
#pragma unroll
    for (int off = 32; off; off >>= 1) {
      unsigned long long o = __shfl_xor(best, off);
      if (o > best) best = o;
    }
    if (lane == 0) wred[wid] = best;
    __syncthreads();
    if (t == 0) {
      unsigned long long b0 = wred[0];
      if (wred[1] > b0) b0 = wred[1];
      if (wred[2] > b0) b0 = wred[2];
      if (wred[3] > b0) b0 = wred[3];
      sbest = b0;
      mtop[bh * NS + it] = (int)(~(unsigned)(b0 & 0xFFFFFFFFull));
    }
    __syncthreads();
    unsigned long long bb = sbest;     // keys are unique -> exact match zeroing
    if (t < 8 * NS && keys[t] == bb) keys[t] = 0;
    if (t + 256 < 8 * NS && keys[t + 256] == bb) keys[t + 256] = 0;
    __syncthreads();
  }
}

// ---------------- K3a: partial mean of v over l ----------------
// grid (32 bh, 64 chunks); block sums 64 consecutive l rows.
__global__ __launch_bounds__(256) void k_meanv_part(
    const float* __restrict__ v, float* __restrict__ vpart)
{
  __shared__ float part[4][ND];
  int bh = blockIdx.x, c = blockIdx.y;
  int b = bh >> 3, h = bh & 7;
  int t = threadIdx.x, d = t & 63, g = t >> 6;
  float a0 = 0.f, a1 = 0.f, a2 = 0.f, a3 = 0.f;
  const float* vb = v + ((size_t)(b * NL + c * 64) * NH + h) * ND + d;
#pragma unroll
  for (int i = 0; i < 4; i++) {
    a0 += vb[(size_t)(g + 4 * (4 * i + 0)) * NH * ND];
    a1 += vb[(size_t)(g + 4 * (4 * i + 1)) * NH * ND];
    a2 += vb[(size_t)(g + 4 * (4 * i + 2)) * NH * ND];
    a3 += vb[(size_t)(g + 4 * (4 * i + 3)) * NH * ND];
  }
  part[g][d] = (a0 + a1) + (a2 + a3);
  __syncthreads();
  if (g == 0) {
    float s = part[0][d] + part[1][d] + part[2][d] + part[3][d];
    vpart[(bh * 64 + c) * ND + d] = s;
  }
}

// ---------------- K3b: reduce partials -> meanv ----------------
__global__ __launch_bounds__(64) void k_meanv_final(
    const float* __restrict__ vpart, float* __restrict__ meanv)
{
  int bh = blockIdx.x, d = threadIdx.x;
  float s = 0.f;
  for (int c = 0; c < 64; c++) s += vpart[(bh * 64 + c) * ND + d];
  meanv[bh * ND + d] = s * (1.0f / 4096.0f);
}

// ---------------- K3c: fill output with meanv ----------------
__global__ __launch_bounds__(256) void k_fill(
    const float* __restrict__ meanv, float4* __restrict__ out4)
{
  const int total = NB * NH * NL * ND / 4;  // 2M float4
  const float4* mv4 = (const float4*)meanv;
  for (int i = blockIdx.x * 256 + threadIdx.x; i < total; i += gridDim.x * 256) {
    int bh = i >> 16;       // 65536 float4 per (b,h)
    int d4 = i & 15;
    out4[i] = mv4[bh * 16 + d4];
  }
}

// ---------------- K4: split-K scores+softmax+PV partials ----------------
// Block = (b,h, chunk of 256 keys), 256 threads (4 waves).
__global__ __launch_bounds__(256) void k_scores(
    const float* __restrict__ q, const float* __restrict__ k,
    const float* __restrict__ v, const int* __restrict__ mtop,
    float* __restrict__ mc_out, float* __restrict__ lc_out,
    float* __restrict__ op_out)
{
  __shared__ float QLDS[NS * ND];     // 45x64
  __shared__ float SLDS[NS * 260];    // 45 rows, 260-stride (pad), cols 0..255
  __shared__ int mt[NS];
  __shared__ float mcs[NS], lcs[NS];

  int gb = blockIdx.x;
  int xcd = gb & 7, seq = gb >> 3;    // 512 blocks: 4 bh per XCD
  int bh = xcd * 4 + (seq >> 4);
  int c = seq & 15;
  int b = bh >> 3, h = bh & 7;
  int t = threadIdx.x;
  int wid = t >> 6, lane = t & 63;

  if (t < NS) mt[t] = mtop[bh * NS + t];
  __syncthreads();

  // stage Qr (45 rows) into LDS
  const float4* q4 = (const float4*)q;
  float4* QL4 = (float4*)QLDS;
  for (int i = t; i < NS * 16; i += 256) {
    int u = i >> 4, j = i & 15;
    QL4[i] = q4[((size_t)(b * NL + mt[u]) * NH + h) * 16 + j];
  }
  __syncthreads();

  // Phase B: thread t owns key column kk=t; K row held in 16 float4 regs.
  {
    int kk = t;
    const float4* k4 =
        (const float4*)(k + ((size_t)(b * NL + c * CHUNK + kk) * NH + h) * ND);
    float4 kr[16];
#pragma unroll
    for (int j = 0; j < 16; j++) kr[j] = k4[j];
    for (int u = 0; u < NS; ++u) {
      float dot = 0.f;
#pragma unroll
      for (int j = 0; j < 16; j++) {
        float4 qq = QL4[u * 16 + j];  // broadcast read
        dot += qq.x * kr[j].x + qq.y * kr[j].y + qq.z * kr[j].z + qq.w * kr[j].w;
      }
      SLDS[u * 260 + kk] = dot * SCALE;
    }
  }
  __syncthreads();

  // Phase B2: per-row chunk softmax (max, exp, sum), exp written back.
  for (int u = wid; u < NS; u += 4) {
    float4 sv = *(const float4*)&SLDS[u * 260 + lane * 4];
    float mx = fmaxf(fmaxf(sv.x, sv.y), fmaxf(sv.z, sv.w));
#pragma unroll
    for (int off = 32; off; off >>= 1) mx = fmaxf(mx, __shfl_xor(mx, off));
    float e0 = expf(sv.x - mx), e1 = expf(sv.y - mx);
    float e2 = expf(sv.z - mx), e3 = expf(sv.w - mx);
    float s = e0 + e1 + e2 + e3;
#pragma unroll
    for (int off = 32; off; off >>= 1) s += __shfl_xor(s, off);
    *(float4*)&SLDS[u * 260 + lane * 4] = make_float4(e0, e1, e2, e3);
    if (lane == 0) { mcs[u] = mx; lcs[u] = s; }
  }
  __syncthreads();

  // Phase C: O_partial = P @ V_chunk. Wave w owns rows u = w+4i; lane = d.
  float acc[12];
#pragma unroll
  for (int i = 0; i < 12; i++) acc[i] = 0.f;
  const float* vbase = v + ((size_t)(b * NL + c * CHUNK) * NH + h) * ND + lane;
  for (int kb = 0; kb < 64; ++kb) {
    float vd0 = vbase[(size_t)(kb * 4 + 0) * NH * ND];
    float vd1 = vbase[(size_t)(kb * 4 + 1) * NH * ND];
    float vd2 = vbase[(size_t)(kb * 4 + 2) * NH * ND];
    float vd3 = vbase[(size_t)(kb * 4 + 3) * NH * ND];
#pragma unroll
    for (int i = 0; i < 12; i++) {
      int u = wid + 4 * i;
      if (u < NS) {
        float4 p4 = *(const float4*)&SLDS[u * 260 + kb * 4];  // broadcast
        acc[i] += p4.x * vd0 + p4.y * vd1 + p4.z * vd2 + p4.w * vd3;
      }
    }
  }
#pragma unroll
  for (int i = 0; i < 12; i++) {
    int u = wid + 4 * i;
    if (u < NS)
      op_out[(((size_t)bh * NCHUNK + c) * NS + u) * ND + lane] = acc[i];
  }
  if (t < NS) {
    mc_out[(bh * NCHUNK + c) * NS + t] = mcs[t];
    lc_out[(bh * NCHUNK + c) * NS + t] = lcs[t];
  }
}

// ---------------- K5: combine partials + scatter ----------------
__global__ __launch_bounds__(256) void k_combine(
    const float* __restrict__ mc, const float* __restrict__ lc,
    const float* __restrict__ op, const int* __restrict__ mtop,
    float* __restrict__ out)
{
  int gw = blockIdx.x * 4 + (threadIdx.x >> 6);  // 1440 waves
  int lane = threadIdx.x & 63;
  int bh = gw / NS, u = gw % NS;
  float M = neg_inf();
  for (int c = 0; c < NCHUNK; c++)
    M = fmaxf(M, mc[(bh * NCHUNK + c) * NS + u]);
  float Lsum = 0.f, O = 0.f;
  for (int c = 0; c < NCHUNK; c++) {
    float e = expf(mc[(bh * NCHUNK + c) * NS + u] - M);
    Lsum += lc[(bh * NCHUNK + c) * NS + u] * e;
    O += op[(((size_t)bh * NCHUNK + c) * NS + u) * ND + lane] * e;
  }
  int row = mtop[bh * NS + u];
  out[((size_t)bh * NL + row) * ND + lane] = O / Lsum;
}

extern "C" void kernel_launch(void* const* d_in, const int* in_sizes, int n_in,
                              void* d_out, int out_size, void* d_ws, size_t ws_size,
                              hipStream_t stream) {
  const float* q = (const float*)d_in[0];
  const float* k = (const float*)d_in[1];
  const float* v = (const float*)d_in[2];
  const int* idxs = (const int*)d_in[3];
  float* out = (float*)d_out;
  float* ws = (float*)d_ws;

  // workspace layout (floats): total ~1.66M floats = 6.62 MB
  float* m_ws  = ws;                    // 131072
  int*   mtop  = (int*)(ws + 131072);   // 1440 ints
  float* meanv = ws + 132512;           // 2048
  float* mc    = ws + 134560;           // 32*16*45 = 23040
  float* lc    = ws + 157600;           // 23040
  float* op    = ws + 180640;           // 32*16*45*64 = 1474560
  // Aliases inside op (consumed before k_scores writes op; serial stream):
  //   vpart: op[0 .. 131072)           (meanv partials)
  //   cand : op[131072 .. 154112)      (topk candidates, 11520 u64)
  float* vpart = op;
  unsigned long long* cand = (unsigned long long*)(op + 131072);

  hipLaunchKernelGGL(k_compute_m,   dim3(8192),      dim3(256), 0, stream, q, k, idxs, m_ws);
  hipLaunchKernelGGL(k_topk_p1,     dim3(256),       dim3(256), 0, stream, m_ws, cand);
  hipLaunchKernelGGL(k_topk_p2,     dim3(32),        dim3(256), 0, stream, cand, mtop);
  hipLaunchKernelGGL(k_meanv_part,  dim3(32, 64),    dim3(256), 0, stream, v, vpart);
  hipLaunchKernelGGL(k_meanv_final, dim3(32),        dim3(64),  0, stream, vpart, meanv);
  hipLaunchKernelGGL(k_fill,        dim3(2048),      dim3(256), 0, stream, meanv, (float4*)out);
  hipLaunchKernelGGL(k_scores,      dim3(512),       dim3(256), 0, stream, q, k, v, mtop, mc, lc, op);
  hipLaunchKernelGGL(k_combine,     dim3(360),       dim3(256), 0, stream, mc, lc, op, mtop, out);
}